// Round 13
// baseline (233.472 us; speedup 1.0000x reference)
//
#include <hip/hip_runtime.h>
#include <math.h>

// IPA: B=1, N=768, H=12, C=16, PQ=4, PV=8, C_S=384, C_Z=128
// ws layout (floats):
#define RAW_OFF    0u          // [768][1152] q|k|v|qp|kp|vp
#define QPTS_OFF   884736u     // [768][144]
#define KPTS_OFF   995328u     // [768][144]
#define VPTS_OFF   1105920u    // [768][288]
#define QN_OFF     1327104u    // [768][12]
#define KN_OFF     1336320u    // [768][12]
#define CAT_OFF    1345536u    // bf16 [768][2016] (u16 in f32 slots)
#define QP_OFF     2893824u    // bf16 [768][12][32]
#define KP_OFF     3041280u    // bf16 [768][12][32]
#define SLOG2_OFF  3188736u    // f32 [768][12 mtile][16 h][64 mlocal] = 9437184
#define PART2_OFF  12625920u   // f32 [1536][2508] ipa partials
#define WT_OFF     16478208u   // bf16 [384][2016] W_out transposed

#define WL 0.5773502691896258f
#define WC 0.23570226039551587f
#define CKN (-0.5f*WL*WC)

typedef __attribute__((ext_vector_type(8))) short short8;
typedef __attribute__((ext_vector_type(4))) float f32x4;

__device__ __forceinline__ unsigned short f2bf1(float a) {
  unsigned u = __builtin_bit_cast(unsigned, a);
  return (unsigned short)((u + 0x7fff + ((u >> 16) & 1)) >> 16);
}
__device__ __forceinline__ unsigned f2bf2(float a, float b) {
  unsigned ua = __builtin_bit_cast(unsigned, a), ub = __builtin_bit_cast(unsigned, b);
  return (unsigned)((ua + 0x7fff + ((ua >> 16) & 1)) >> 16)
       | ((ub + 0x7fff + ((ub >> 16) & 1)) & 0xffff0000u);
}
__device__ __forceinline__ float bf2f(unsigned short u) {
  return __builtin_bit_cast(float, ((unsigned)u) << 16);
}

// LDS-only barrier in ONE asm (raw s_barrier is not a compiler fence).
// Leaves global loads (vmcnt) in flight across it.
#define BAR_LDS() asm volatile("s_waitcnt lgkmcnt(0)\n\ts_barrier" ::: "memory")

// ---------------- kernel 0: W_out transpose to bf16 (independent; launched first) ----
__global__ __launch_bounds__(256) void wcvt(
    const float* __restrict__ Wout, unsigned short* __restrict__ WT)
{
  __shared__ float tl[32][33];
  int b = blockIdx.x;
  int kt = b % 63, ct = b / 63;
  int k0 = kt*32, c0 = ct*32;
  int tr = threadIdx.x >> 5, tc = threadIdx.x & 31;
  #pragma unroll
  for (int i = 0; i < 4; ++i)
    tl[tr + i*8][tc] = Wout[(size_t)(k0 + tr + i*8)*384 + c0 + tc];
  __syncthreads();
  #pragma unroll
  for (int i = 0; i < 4; ++i) {
    int c = tr + i*8;
    WT[(size_t)(c0 + c)*2016 + k0 + tc] = f2bf1(tl[tc][c]);
  }
}

// ---------------- kernel 1: s @ [Wq|Wk|Wv|Wqp|Wkp|Wvp] -> raw ----------------
__global__ __launch_bounds__(256) void prep_gemm(
    const float* __restrict__ s, const float* __restrict__ Wq, const float* __restrict__ Wk,
    const float* __restrict__ Wv, const float* __restrict__ Wqp, const float* __restrict__ Wkp,
    const float* __restrict__ Wvp, float* __restrict__ raw)
{
  int t = threadIdx.x;
  int bc = blockIdx.x % 24, br = blockIdx.x / 24;
  int row0 = br * 32, cb = bc * 48;
  const float* W; int outdim, c0;
  if (cb < 192)      { W = Wq;  outdim = 192; c0 = cb; }
  else if (cb < 384) { W = Wk;  outdim = 192; c0 = cb - 192; }
  else if (cb < 576) { W = Wv;  outdim = 192; c0 = cb - 384; }
  else if (cb < 720) { W = Wqp; outdim = 144; c0 = cb - 576; }
  else if (cb < 864) { W = Wkp; outdim = 144; c0 = cb - 720; }
  else               { W = Wvp; outdim = 288; c0 = cb - 864; }

  __shared__ float s_l[32*33];
  __shared__ float w_l[32*49];
  float acc[2][3] = {};
  int tr = t >> 4, tc = t & 15;

  for (int k0 = 0; k0 < 384; k0 += 32) {
    #pragma unroll
    for (int i = 0; i < 4; ++i) {
      int idx = i*256 + t, r = idx >> 5, kk = idx & 31;
      s_l[r*33 + kk] = s[(row0 + r)*384 + k0 + kk];
    }
    #pragma unroll
    for (int i = 0; i < 6; ++i) {
      int idx = i*256 + t, kk = idx / 48, c = idx % 48;
      w_l[kk*49 + c] = W[(k0 + kk)*outdim + c0 + c];
    }
    __syncthreads();
    #pragma unroll
    for (int kk = 0; kk < 32; ++kk) {
      float a0 = s_l[(tr*2+0)*33 + kk], a1 = s_l[(tr*2+1)*33 + kk];
      float b0 = w_l[kk*49 + tc*3 + 0], b1 = w_l[kk*49 + tc*3 + 1], b2 = w_l[kk*49 + tc*3 + 2];
      acc[0][0] += a0*b0; acc[0][1] += a0*b1; acc[0][2] += a0*b2;
      acc[1][0] += a1*b0; acc[1][1] += a1*b1; acc[1][2] += a1*b2;
    }
    __syncthreads();
  }
  #pragma unroll
  for (int i = 0; i < 2; ++i)
    #pragma unroll
    for (int j = 0; j < 3; ++j)
      raw[(row0 + tr*2 + i)*1152 + cb + tc*3 + j] = acc[i][j];
}

// ---------------- kernel 2: frame transform + point norms ----------------
__global__ __launch_bounds__(256) void transform_pts(
    const float* __restrict__ raw, const float* __restrict__ R, const float* __restrict__ tg,
    float* __restrict__ qpts, float* __restrict__ kpts, float* __restrict__ vpts,
    float* __restrict__ qn, float* __restrict__ kn)
{
  int n = blockIdx.x, t = threadIdx.x;
  __shared__ float tl[576];
  const float* R9 = R + n*9;
  const float* tv = tg + n*3;
  for (int i = 0; i < 3; ++i) {
    int j = i*256 + t;
    if (j >= 576) break;
    int jj, basecol; float* dst; int dstoff;
    if (j < 144)      { jj = j;      basecol = 576; dst = qpts; dstoff = n*144 + jj; }
    else if (j < 288) { jj = j-144;  basecol = 720; dst = kpts; dstoff = n*144 + jj; }
    else              { jj = j-288;  basecol = 864; dst = vpts; dstoff = n*288 + jj; }
    int x = jj % 3;
    const float* p = raw + n*1152 + basecol + (jj - x);
    float val = R9[x*3+0]*p[0] + R9[x*3+1]*p[1] + R9[x*3+2]*p[2] + tv[x];
    dst[dstoff] = val;
    tl[j] = val;
  }
  __syncthreads();
  if (t < 24) {
    int side = t / 12, h = t % 12;
    const float* q = tl + side*144 + h*12;
    float sm = 0.f;
    #pragma unroll
    for (int r = 0; r < 12; ++r) sm += q[r]*q[r];
    (side == 0 ? qn : kn)[n*12 + h] = sm;
  }
}

// ---------------- kernel 3: build Qp/Kp bf16 [n][h][32] ----------------
__global__ __launch_bounds__(384) void qkprep(
    const float* __restrict__ raw, const float* __restrict__ qpts,
    const float* __restrict__ kpts, short* __restrict__ Qp, short* __restrict__ Kp)
{
  int n = blockIdx.x, t = threadIdx.x;
  int h = t >> 5, k = t & 31;
  float qv, kv;
  // raw cols: q 0..191, k 192..383, v 384..575
  if (k < 16)      { qv = (WL*0.25f) * raw[n*1152 + h*16 + k];       kv = raw[n*1152 + 192 + h*16 + k]; }
  else if (k < 28) { qv = (WL*WC) * qpts[n*144 + h*12 + (k-16)];     kv = kpts[n*144 + h*12 + (k-16)]; }
  else             { qv = 0.f; kv = 0.f; }
  Qp[n*384 + t] = (short)f2bf1(qv);
  Kp[n*384 + t] = (short)f2bf1(kv);
}

// ---------------- kernel 4: slog2 = logits via per-h bf16 MFMA GEMM ----------------
// Output layout [n][mtile][h(16)][mlocal(64)] so ipa's register-bias consumer
// (thread (wid,kg,l15) owning m=wid*16+kg*4+r, h=l15) reads ONE contiguous float4.
__global__ __launch_bounds__(512) void logits_gemm(
    const short* __restrict__ Qp, const short* __restrict__ Kp,
    const float* __restrict__ kn, float* __restrict__ slog2)
{
  int t = threadIdx.x, b = blockIdx.x;
  int bn = b / 12, bm = b % 12;
  int lane = t & 63, wid = t >> 6;
  int nsub = wid & 3, msub = wid >> 2;
  int l15 = lane & 15, kg = lane >> 4;
  int nrow = bn*64 + nsub*16 + l15;
  int mbase = bm*64 + msub*32;

  f32x4 acc[2][12];
  #pragma unroll
  for (int mt = 0; mt < 2; ++mt)
    #pragma unroll
    for (int h = 0; h < 12; ++h) acc[mt][h] = (f32x4){0.f,0.f,0.f,0.f};

  #pragma unroll
  for (int h = 0; h < 12; ++h) {
    short8 af = *(const short8*)(Qp + (size_t)(nrow*12 + h)*32 + kg*8);
    #pragma unroll
    for (int mt = 0; mt < 2; ++mt) {
      int m = mbase + mt*16 + l15;
      short8 bf = *(const short8*)(Kp + (size_t)(m*12 + h)*32 + kg*8);
      acc[mt][h] = __builtin_amdgcn_mfma_f32_16x16x32_bf16(af, bf, acc[mt][h], 0, 0, 0);
    }
  }
  #pragma unroll
  for (int mt = 0; mt < 2; ++mt) {
    int mglob = mbase + mt*16 + l15;
    int mlocal = msub*32 + mt*16 + l15;
    float knadj[12];
    #pragma unroll
    for (int h = 0; h < 12; ++h) knadj[h] = CKN * kn[mglob*12 + h];
    #pragma unroll
    for (int r = 0; r < 4; ++r) {
      int nr = bn*64 + nsub*16 + kg*4 + r;
      size_t base = ((size_t)nr*12 + bm)*1024 + mlocal;
      #pragma unroll
      for (int h = 0; h < 12; ++h)
        slog2[base + h*64] = acc[mt][h][r] + knadj[h];   // lane-coalesced over l15
    }
  }
}

// ---------------- kernel 5: fused attention core, 2 barriers/iter ----------------
// grid 1536: block bx -> (n = bx>>1, hb = bx&1); 6 of 12 m-tiles each.
// z double-buffered (Z0/Z1); bias MFMA output exp'd IN REGISTERS (slog2 float4
// prefetch matches the MFMA D-layout) -> no BIASL, no B2 phase, S in register.
// Per iter: {B1+exp+pt-write} BAR {C, D, STAGE_WRITE->other buf} BAR.
// LDS words: Z0 [64][68w], Z1 [64][68w], pt bf16 [16][72], S_part[4][12]
#define Z0    0
#define Z1    4352
#define PT_W  8704
#define SPART 9280
#define SMEMW 9328

// launch_bounds min-waves MUST stay <= 2: at >=3 the compiler targets a 64-85
// VGPR budget and spills the 32-reg zst prefetch to scratch (R5 AND R9 both
// hit this: WRITE_SIZE ~0.5 GB, 2x slowdown). VGPR ~115 needs the 2-wave cap.
__global__ __launch_bounds__(256, 2) void ipa_main(
    const float* __restrict__ z, const float* __restrict__ raw,
    const float* __restrict__ slog2, const float* __restrict__ vpts,
    const float* __restrict__ Wb, float* __restrict__ part2)
{
  __shared__ __align__(16) unsigned smem[SMEMW];
  float* smf = (float*)smem;
  unsigned short* lds16 = (unsigned short*)smem;
  int bx = blockIdx.x;
  int n = bx >> 1, hb = bx & 1;
  int t = threadIdx.x;
  int lane = t & 63, wid = t >> 6;
  int l15 = lane & 15, kg = lane >> 4;

  // Wb fragments (WL folded), bf16; cols l15>=12 zero
  short8 wbf[4];
  {
    #pragma unroll
    for (int ks = 0; ks < 4; ++ks)
      #pragma unroll
      for (int e = 0; e < 8; ++e) {
        int kk = ks*32 + kg*8 + e;
        float v = (l15 < 12) ? WL * Wb[kk*12 + l15] : 0.f;
        wbf[ks][e] = (short)f2bf1(v);
      }
  }

  // C-phase (MFMA): wave owns zc-tiles {wid*2, wid*2+1}
  f32x4 oacc[2];
  oacc[0] = (f32x4){0.f,0.f,0.f,0.f};
  oacc[1] = (f32x4){0.f,0.f,0.f,0.f};
  float sacc = 0.f;   // per-thread softmax-denominator partial (h = l15)

  // D-phase: 120 float4-columns of [v|vpts] x 2 m-halves
  bool dact = t < 240;
  int mh = t / 120, slot = t % 120;
  const float* dsrc; int dstride, dh;
  if (slot < 48) { dh = slot >> 2;     dsrc = raw + 384 + slot*4;  dstride = 1152; }
  else           { dh = (slot-48) / 6; dsrc = vpts + (slot-48)*4;  dstride = 288;  }
  float da0 = 0.f, da1 = 0.f, da2 = 0.f, da3 = 0.f;

  const float* zrow = z + (size_t)n*768*128;
  int ssm = t >> 5, ssc = t & 31;

  float4 zst[8];
  #define STAGE_LOAD(M0)                                                     \
    _Pragma("unroll")                                                        \
    for (int i = 0; i < 8; ++i)                                              \
      zst[i] = *(const float4*)(zrow + (size_t)((M0) + i*8 + ssm)*128 + ssc*4);
  #define STAGE_WRITE(BASE)                                                  \
    _Pragma("unroll")                                                        \
    for (int i = 0; i < 8; ++i) {                                            \
      unsigned w0 = f2bf2(zst[i].x, zst[i].y);                               \
      unsigned w1 = f2bf2(zst[i].z, zst[i].w);                               \
      uint2 uu; uu.x = w0; uu.y = w1;                                        \
      *(uint2*)&smem[(BASE) + (i*8 + ssm)*68 + ssc*2] = uu;                  \
    }

  // slog2 prefetch: one float4 per thread, layout-matched to bias MFMA output:
  // thread (wid,kg,l15) -> bias rows m = wid*16+kg*4+r (r=0..3), h = l15.
  const size_t slb2 = (size_t)n * 12288;   // 12 tiles x 1024
  float4 sl, slnx;
  #define SLOG_LOAD(DST, TILE)                                               \
    DST = *(const float4*)(slog2 + slb2 + (size_t)(TILE)*1024 + l15*64 + wid*16 + kg*4);

  STAGE_LOAD(hb*384);
  SLOG_LOAD(sl, hb*6);
  STAGE_WRITE(Z0);
  BAR_LDS();

  for (int it = 0; it < 6; ++it) {
    int m0 = hb*384 + it*64;
    int cur = (it & 1) ? Z1 : Z0;
    int nxt = (it & 1) ? Z0 : Z1;
    if (it < 5) { STAGE_LOAD(m0 + 64); SLOG_LOAD(slnx, hb*6 + it + 1); }

    // ---- segment A: bias MFMA + exp in regs + pt write ----
    {
      f32x4 bacc = (f32x4){0.f,0.f,0.f,0.f};
      int zbase = cur + (wid*16 + l15)*68;
      #pragma unroll
      for (int ks = 0; ks < 4; ++ks) {
        short8 za = *(const short8*)&smem[zbase + kg*4 + ks*16];
        bacc = __builtin_amdgcn_mfma_f32_16x16x32_bf16(za, wbf[ks], bacc, 0, 0, 0);
      }
      float slv[4] = {sl.x, sl.y, sl.z, sl.w};
      float pr[4];
      #pragma unroll
      for (int r = 0; r < 4; ++r) pr[r] = __expf(slv[r] + bacc[r]);
      sacc += pr[0] + pr[1] + pr[2] + pr[3];
      uint2 pk; pk.x = f2bf2(pr[0], pr[1]); pk.y = f2bf2(pr[2], pr[3]);
      *(uint2*)&lds16[PT_W*2 + l15*72 + wid*16 + kg*4] = pk;
    }
    BAR_LDS();

    // ---- segment B: C (o_pair MFMA), D (o/o_pts), stage next tile ----
    {
      short8 af[2];
      #pragma unroll
      for (int ks = 0; ks < 2; ++ks)
        af[ks] = *(const short8*)&lds16[PT_W*2 + l15*72 + ks*32 + kg*8];
      #pragma unroll
      for (int tt = 0; tt < 2; ++tt) {
        int zc = (wid*2 + tt)*16 + l15;
        #pragma unroll
        for (int ks = 0; ks < 2; ++ks) {
          short8 bf;
          #pragma unroll
          for (int e = 0; e < 8; ++e)
            bf[e] = (short)lds16[cur*2 + (ks*32 + kg*8 + e)*136 + zc];
          oacc[tt] = __builtin_amdgcn_mfma_f32_16x16x32_bf16(af[ks], bf, oacc[tt], 0, 0, 0);
        }
      }
    }
    if (dact) {
      #pragma unroll
      for (int j4 = 0; j4 < 4; ++j4) {
        short8 pw = *(const short8*)&lds16[PT_W*2 + dh*72 + mh*32 + j4*8];
        #pragma unroll
        for (int e = 0; e < 8; ++e) {
          float wq = bf2f((unsigned short)pw[e]);
          int row = m0 + mh*32 + j4*8 + e;
          float4 v = *(const float4*)(dsrc + (size_t)row*dstride);
          da0 += wq*v.x; da1 += wq*v.y; da2 += wq*v.z; da3 += wq*v.w;
        }
      }
    }
    if (it < 5) {
      STAGE_WRITE(nxt);
      sl = slnx;
    }
    BAR_LDS();
  }

  // ---- finalize: reduce S, dump partials ----
  sacc += __shfl_xor(sacc, 16);
  sacc += __shfl_xor(sacc, 32);
  if (lane < 12) smf[SPART + wid*12 + lane] = sacc;
  BAR_LDS();

  float* pb = part2 + (size_t)bx * 2508;
  if (t < 12)
    pb[t] = smf[SPART + t] + smf[SPART + 12 + t] + smf[SPART + 24 + t] + smf[SPART + 36 + t];
  if (dact) {
    float4 dv; dv.x = da0; dv.y = da1; dv.z = da2; dv.w = da3;
    *(float4*)(pb + 12 + (mh*120 + slot)*4) = dv;
  }
  if (kg < 3) {
    #pragma unroll
    for (int tt = 0; tt < 2; ++tt) {
      int zc = (wid*2 + tt)*16 + l15;
      #pragma unroll
      for (int r = 0; r < 4; ++r)
        pb[972 + (kg*4 + r)*128 + zc] = oacc[tt][r];
    }
  }
}

// ---------------- kernel 5b: combine halves, normalize, inverse-frame -> catb (bf16) ----------------
__global__ __launch_bounds__(256) void combine(
    const float* __restrict__ part2, const float* __restrict__ Rg,
    const float* __restrict__ tg, unsigned short* __restrict__ catb)
{
  int n = blockIdx.x, t = threadIdx.x;
  const float* b0 = part2 + (size_t)n*2*2508;
  const float* b1 = b0 + 2508;
  __shared__ float S[12], ogl[288];
  if (t < 12) S[t] = b0[t] + b1[t];
  __syncthreads();
  unsigned short* cb = catb + (size_t)n*2016;
  for (int i = t; i < 480; i += 256) {
    float v = b0[12+i] + b0[12+480+i] + b1[12+i] + b1[12+480+i];
    int slot = i >> 2;
    int dh = (slot < 48) ? (slot >> 2) : ((slot - 48) / 6);
    float val = v / S[dh];
    if (i < 192) cb[i] = f2bf1(val);
    else         ogl[i - 192] = val;
  }
  __syncthreads();
  const float* R9 = Rg + n*9;
  const float* tv = tg + n*3;
  for (int j = t; j < 288; j += 256) {
    int x = j % 3, base = j - x;
    float g0 = ogl[base+0] - tv[0];
    float g1 = ogl[base+1] - tv[1];
    float g2 = ogl[base+2] - tv[2];
    cb[192 + j] = f2bf1(R9[x]*g0 + R9[3+x]*g1 + R9[6+x]*g2);   // R^T (g - t)
  }
  for (int e = t; e < 1536; e += 256) {
    int h = e >> 7;
    cb[480 + e] = f2bf1((b0[972+e] + b1[972+e]) / S[h]);
  }
}

// ---------------- kernel 6: out = catb @ WT^T + b_out via bf16 MFMA ----------------
__global__ __launch_bounds__(256) void final_mfma(
    const unsigned short* __restrict__ catb, const unsigned short* __restrict__ WT,
    const float* __restrict__ bout, float* __restrict__ out)
{
  int t = threadIdx.x, b = blockIdx.x;
  int rt = b / 6, ct = b % 6;
  int r0 = rt*64, c0 = ct*64;
  int lane = t & 63, wid = t >> 6;
  int l15 = lane & 15, kg = lane >> 4;

  f32x4 acc[4];
  #pragma unroll
  for (int cs = 0; cs < 4; ++cs) acc[cs] = (f32x4){0.f,0.f,0.f,0.f};

  const unsigned short* arow = catb + (size_t)(r0 + wid*16 + l15)*2016;
  for (int k0 = 0; k0 < 2016; k0 += 32) {
    short8 af = *(const short8*)(arow + k0 + kg*8);
    #pragma unroll
    for (int cs = 0; cs < 4; ++cs) {
      short8 bf = *(const short8*)(WT + (size_t)(c0 + cs*16 + l15)*2016 + k0 + kg*8);
      acc[cs] = __builtin_amdgcn_mfma_f32_16x16x32_bf16(af, bf, acc[cs], 0, 0, 0);
    }
  }
  #pragma unroll
  for (int cs = 0; cs < 4; ++cs) {
    #pragma unroll
    for (int r = 0; r < 4; ++r) {
      int nn = r0 + wid*16 + kg*4 + r;
      int c  = c0 + cs*16 + l15;
      out[(size_t)nn*384 + c] = acc[cs][r] + bout[c];
    }
  }
}

extern "C" void kernel_launch(void* const* d_in, const int* in_sizes, int n_in,
                              void* d_out, int out_size, void* d_ws, size_t ws_size,
                              hipStream_t stream) {
  const float* s    = (const float*)d_in[0];
  const float* z    = (const float*)d_in[1];
  const float* R    = (const float*)d_in[2];
  const float* tv   = (const float*)d_in[3];
  const float* Wq   = (const float*)d_in[4];
  const float* Wk   = (const float*)d_in[5];
  const float* Wv   = (const float*)d_in[6];
  const float* Wqp  = (const float*)d_in[7];
  const float* Wkp  = (const float*)d_in[8];
  const float* Wvp  = (const float*)d_in[9];
  const float* Wb   = (const float*)d_in[10];
  const float* Wout = (const float*)d_in[11];
  const float* bout = (const float*)d_in[12];
  float* out = (float*)d_out;
  float* ws  = (float*)d_ws;

  float* raw  = ws + RAW_OFF;
  float* qpts = ws + QPTS_OFF;
  float* kpts = ws + KPTS_OFF;
  float* vpts = ws + VPTS_OFF;
  float* qn   = ws + QN_OFF;
  float* kn   = ws + KN_OFF;
  unsigned short* catb = (unsigned short*)(ws + CAT_OFF);
  short* Qp   = (short*)(ws + QP_OFF);
  short* Kp   = (short*)(ws + KP_OFF);
  float* slog2 = ws + SLOG2_OFF;
  float* part2 = ws + PART2_OFF;
  unsigned short* WT = (unsigned short*)(ws + WT_OFF);

  wcvt<<<756, 256, 0, stream>>>(Wout, WT);             // independent; overlaps prep chain
  prep_gemm<<<576, 256, 0, stream>>>(s, Wq, Wk, Wv, Wqp, Wkp, Wvp, raw);
  transform_pts<<<768, 256, 0, stream>>>(raw, R, tv, qpts, kpts, vpts, qn, kn);
  qkprep<<<768, 384, 0, stream>>>(raw, qpts, kpts, Qp, Kp);
  logits_gemm<<<144, 512, 0, stream>>>(Qp, Kp, kn, slog2);
  ipa_main<<<1536, 256, 0, stream>>>(z, raw, slog2, vpts, Wb, part2);
  combine<<<768, 256, 0, stream>>>(part2, R, tv, catb);
  final_mfma<<<72, 256, 0, stream>>>(catb, WT, bout, out);
}

// Round 15
// 201.595 us; speedup vs baseline: 1.1581x; 1.1581x over previous
//
#include <hip/hip_runtime.h>
#include <math.h>

// IPA: B=1, N=768, H=12, C=16, PQ=4, PV=8, C_S=384, C_Z=128
// ws layout (floats). NOTE R14 BUG: bf16 buffers need elemcount/2 f32 SLOTS --
// QP/KP/SB were allotted half their size (Kp ran into slog -> race -> NaN).
#define RAW_OFF    0u          // f32 [768][1152] q|k|v|qp|kp|vp          (884736)
#define VPTS_OFF   884736u     // f32 [768][288]                          (221184)
#define KN_OFF     1105920u    // f32 [768][12]                           (9216)
#define CAT_OFF    1115136u    // bf16 [768][2016] = 1548288 u16          (774144)
#define QP_OFF     1889280u    // bf16 [768][12][32] = 294912 u16         (147456)
#define KP_OFF     2036736u    // bf16 [768][12][32]                      (147456)
#define SLOG_OFF   2184192u    // f32 [768][768][12]                      (7077888)
#define PART2_OFF  9262080u    // f32 [1536][2508]                        (3852288)
#define WT_OFF     13114368u   // bf16 [384][2016] W_out^T = 774144 u16   (387072)
#define SB_OFF     13501440u   // bf16 [768][384] s = 294912 u16          (147456)
#define WTC_OFF    13648896u   // bf16 [1152][384] = 442368 u16           (221184)
// total 13,870,080 floats = 55.5 MB

#define WL 0.5773502691896258f
#define WC 0.23570226039551587f
#define CKN (-0.5f*WL*WC)

typedef __attribute__((ext_vector_type(8))) short short8;
typedef __attribute__((ext_vector_type(4))) float f32x4;

__device__ __forceinline__ unsigned short f2bf1(float a) {
  unsigned u = __builtin_bit_cast(unsigned, a);
  return (unsigned short)((u + 0x7fff + ((u >> 16) & 1)) >> 16);
}
__device__ __forceinline__ unsigned f2bf2(float a, float b) {
  unsigned ua = __builtin_bit_cast(unsigned, a), ub = __builtin_bit_cast(unsigned, b);
  return (unsigned)((ua + 0x7fff + ((ua >> 16) & 1)) >> 16)
       | ((ub + 0x7fff + ((ub >> 16) & 1)) & 0xffff0000u);
}
__device__ __forceinline__ float bf2f(unsigned short u) {
  return __builtin_bit_cast(float, ((unsigned)u) << 16);
}

// LDS-only barrier in ONE asm (raw s_barrier is not a compiler fence).
// Leaves global loads (vmcnt) in flight across it.
#define BAR_LDS() asm volatile("s_waitcnt lgkmcnt(0)\n\ts_barrier" ::: "memory")

// ---------------- kernel 0a: s -> bf16 ----------------
__global__ __launch_bounds__(256) void scvt(
    const float* __restrict__ s, unsigned short* __restrict__ sb)
{
  int g = blockIdx.x*256 + threadIdx.x;       // 73728 threads x 4 elems
  float4 v = *(const float4*)(s + (size_t)g*4);
  uint2 p; p.x = f2bf2(v.x, v.y); p.y = f2bf2(v.z, v.w);
  *(uint2*)(sb + (size_t)g*4) = p;
}

// ---------------- kernel 0b: [Wq|Wk|Wv|Wqp|Wkp|Wvp]^T -> bf16 WTc[1152][384] ----------------
__global__ __launch_bounds__(256) void wcatcvt(
    const float* __restrict__ Wq, const float* __restrict__ Wk, const float* __restrict__ Wv,
    const float* __restrict__ Wqp, const float* __restrict__ Wkp, const float* __restrict__ Wvp,
    unsigned short* __restrict__ wtc)
{
  int g = blockIdx.x*256 + threadIdx.x;       // 110592 threads: c = g/96, kq = (g%96)*4
  int c = g / 96, kq = (g % 96) * 4;
  const float* W; int od, cl;
  if (c < 192)      { W = Wq;  od = 192; cl = c; }
  else if (c < 384) { W = Wk;  od = 192; cl = c - 192; }
  else if (c < 576) { W = Wv;  od = 192; cl = c - 384; }
  else if (c < 720) { W = Wqp; od = 144; cl = c - 576; }
  else if (c < 864) { W = Wkp; od = 144; cl = c - 720; }
  else              { W = Wvp; od = 288; cl = c - 864; }
  float a = W[(size_t)(kq+0)*od + cl];
  float b = W[(size_t)(kq+1)*od + cl];
  float d = W[(size_t)(kq+2)*od + cl];
  float e = W[(size_t)(kq+3)*od + cl];
  uint2 p; p.x = f2bf2(a, b); p.y = f2bf2(d, e);
  *(uint2*)(wtc + (size_t)c*384 + kq) = p;
}

// ---------------- kernel 0c: W_out^T -> bf16 WT[384][2016] ----------------
__global__ __launch_bounds__(256) void wcvt(
    const float* __restrict__ Wout, unsigned short* __restrict__ WT)
{
  __shared__ float tl[32][33];
  int b = blockIdx.x;
  int kt = b % 63, ct = b / 63;
  int k0 = kt*32, c0 = ct*32;
  int tr = threadIdx.x >> 5, tc = threadIdx.x & 31;
  #pragma unroll
  for (int i = 0; i < 4; ++i)
    tl[tr + i*8][tc] = Wout[(size_t)(k0 + tr + i*8)*384 + c0 + tc];
  __syncthreads();
  #pragma unroll
  for (int i = 0; i < 4; ++i) {
    int c = tr + i*8;
    WT[(size_t)(c0 + c)*2016 + k0 + tc] = f2bf1(tl[tc][c]);
  }
}

// ---------------- kernel 1: raw = s @ Wcat via bf16 MFMA (no LDS; L2-resident) ----------------
__global__ __launch_bounds__(256) void prep_mfma(
    const unsigned short* __restrict__ sb, const unsigned short* __restrict__ wtc,
    float* __restrict__ raw)
{
  int t = threadIdx.x, b = blockIdx.x;
  int ct = b % 18, rt = b / 18;           // 12 row-tiles x 18 col-tiles
  int lane = t & 63, wid = t >> 6;
  int l15 = lane & 15, kg = lane >> 4;
  int r0 = rt*64 + wid*16, c0 = ct*64;

  f32x4 acc[4];
  #pragma unroll
  for (int cs = 0; cs < 4; ++cs) acc[cs] = (f32x4){0.f,0.f,0.f,0.f};

  for (int k0 = 0; k0 < 384; k0 += 32) {
    short8 af = *(const short8*)(sb + (size_t)(r0 + l15)*384 + k0 + kg*8);
    #pragma unroll
    for (int cs = 0; cs < 4; ++cs) {
      short8 bf = *(const short8*)(wtc + (size_t)(c0 + cs*16 + l15)*384 + k0 + kg*8);
      acc[cs] = __builtin_amdgcn_mfma_f32_16x16x32_bf16(af, bf, acc[cs], 0, 0, 0);
    }
  }
  #pragma unroll
  for (int cs = 0; cs < 4; ++cs)
    #pragma unroll
    for (int r = 0; r < 4; ++r)
      raw[(size_t)(r0 + kg*4 + r)*1152 + c0 + cs*16 + l15] = acc[cs][r];
}

// ---------------- kernel 2: frame transform + kn + Qp/Kp (merged; qpts/kpts stay in LDS) ----
__global__ __launch_bounds__(256) void transform_qk(
    const float* __restrict__ raw, const float* __restrict__ R, const float* __restrict__ tg,
    float* __restrict__ vpts, float* __restrict__ kn,
    short* __restrict__ Qp, short* __restrict__ Kp)
{
  int n = blockIdx.x, t = threadIdx.x;
  __shared__ float tl[576];
  const float* R9 = R + n*9;
  const float* tv = tg + n*3;
  #pragma unroll
  for (int i = 0; i < 3; ++i) {
    int j = i*256 + t;
    if (j >= 576) break;
    int jj, basecol;
    if (j < 144)      { jj = j;      basecol = 576; }
    else if (j < 288) { jj = j-144;  basecol = 720; }
    else              { jj = j-288;  basecol = 864; }
    int x = jj % 3;
    const float* p = raw + n*1152 + basecol + (jj - x);
    float val = R9[x*3+0]*p[0] + R9[x*3+1]*p[1] + R9[x*3+2]*p[2] + tv[x];
    if (j >= 288) vpts[n*288 + jj] = val;
    tl[j] = val;
  }
  __syncthreads();
  if (t < 12) {
    const float* q = tl + 144 + t*12;
    float sm = 0.f;
    #pragma unroll
    for (int r = 0; r < 12; ++r) sm += q[r]*q[r];
    kn[n*12 + t] = sm;
  }
  #pragma unroll
  for (int i = 0; i < 2; ++i) {
    int idx = i*256 + t;
    if (idx >= 384) break;
    int h = idx >> 5, k = idx & 31;
    float qv, kv;
    if (k < 16)      { qv = (WL*0.25f) * raw[n*1152 + h*16 + k];  kv = raw[n*1152 + 192 + h*16 + k]; }
    else if (k < 28) { qv = (WL*WC) * tl[h*12 + (k-16)];          kv = tl[144 + h*12 + (k-16)]; }
    else             { qv = 0.f; kv = 0.f; }
    Qp[n*384 + idx] = (short)f2bf1(qv);
    Kp[n*384 + idx] = (short)f2bf1(kv);
  }
}

// ---------------- kernel 3: slog = logits via per-h bf16 MFMA GEMM (R12 version) ----------------
__global__ __launch_bounds__(512) void logits_gemm(
    const short* __restrict__ Qp, const short* __restrict__ Kp,
    const float* __restrict__ kn, float* __restrict__ slog)
{
  int t = threadIdx.x, b = blockIdx.x;
  int bn = b / 12, bm = b % 12;
  int lane = t & 63, wid = t >> 6;
  int nsub = wid & 3, msub = wid >> 2;
  int l15 = lane & 15, kg = lane >> 4;
  int nrow = bn*64 + nsub*16 + l15;
  int mbase = bm*64 + msub*32;

  f32x4 acc[2][12];
  #pragma unroll
  for (int mt = 0; mt < 2; ++mt)
    #pragma unroll
    for (int h = 0; h < 12; ++h) acc[mt][h] = (f32x4){0.f,0.f,0.f,0.f};

  #pragma unroll
  for (int h = 0; h < 12; ++h) {
    short8 af = *(const short8*)(Qp + (size_t)(nrow*12 + h)*32 + kg*8);
    #pragma unroll
    for (int mt = 0; mt < 2; ++mt) {
      int m = mbase + mt*16 + l15;
      short8 bf = *(const short8*)(Kp + (size_t)(m*12 + h)*32 + kg*8);
      acc[mt][h] = __builtin_amdgcn_mfma_f32_16x16x32_bf16(af, bf, acc[mt][h], 0, 0, 0);
    }
  }
  #pragma unroll
  for (int mt = 0; mt < 2; ++mt) {
    int m = mbase + mt*16 + l15;
    float knadj[12];
    #pragma unroll
    for (int h = 0; h < 12; ++h) knadj[h] = CKN * kn[m*12 + h];
    #pragma unroll
    for (int r = 0; r < 4; ++r) {
      int nr = bn*64 + nsub*16 + kg*4 + r;
      size_t base = ((size_t)nr*768 + m)*12;
      #pragma unroll
      for (int hq = 0; hq < 3; ++hq) {
        float4 v;
        v.x = acc[mt][hq*4+0][r] + knadj[hq*4+0];
        v.y = acc[mt][hq*4+1][r] + knadj[hq*4+1];
        v.z = acc[mt][hq*4+2][r] + knadj[hq*4+2];
        v.w = acc[mt][hq*4+3][r] + knadj[hq*4+3];
        *(float4*)(slog + base + hq*4) = v;
      }
    }
  }
}

// ---------------- kernel 4: fused attention core (R12 version, proven best) ----------------
// grid 1536: block bx -> (n = bx>>1, hb = bx&1); each handles 6 of 12 m-tiles.
// LDS words: z_l bf16 [64][68w], bias[64][17], pt bf16 [16][72], S[12]
#define Z_L   0
#define BIASL 4352
#define PT    5440
#define S_L   6016
#define SMEMW 6028

// launch_bounds min-waves MUST stay <= 2: at >=3 the compiler targets a 64-85
// VGPR budget and spills the 32-reg zst prefetch to scratch (R5 AND R9 both
// hit this: WRITE_SIZE ~0.5 GB, 2x slowdown). VGPR ~112 needs the 2-wave cap.
__global__ __launch_bounds__(256, 2) void ipa_main(
    const float* __restrict__ z, const float* __restrict__ raw,
    const float* __restrict__ slog, const float* __restrict__ vpts,
    const float* __restrict__ Wb, float* __restrict__ part2)
{
  __shared__ __align__(16) unsigned smem[SMEMW];
  float* smf = (float*)smem;
  unsigned short* lds16 = (unsigned short*)smem;
  int bx = blockIdx.x;
  int n = bx >> 1, hb = bx & 1;
  int t = threadIdx.x;
  int lane = t & 63, wid = t >> 6;
  int l15 = lane & 15, kg = lane >> 4;

  if (t < 12) smf[S_L + t] = 0.f;

  // Wb B-fragments (WL folded), bf16
  short8 wbf[4];
  {
    #pragma unroll
    for (int ks = 0; ks < 4; ++ks)
      #pragma unroll
      for (int e = 0; e < 8; ++e) {
        int kk = ks*32 + kg*8 + e;
        float v = (l15 < 12) ? WL * Wb[kk*12 + l15] : 0.f;
        wbf[ks][e] = (short)f2bf1(v);
      }
  }

  // C-phase (MFMA): wave owns zc-tiles {wid*2, wid*2+1}
  f32x4 oacc[2];
  oacc[0] = (f32x4){0.f,0.f,0.f,0.f};
  oacc[1] = (f32x4){0.f,0.f,0.f,0.f};

  // D-phase: 120 float4-columns of [v|vpts] x 2 m-halves
  bool dact = t < 240;
  int mh = t / 120, slot = t % 120;
  const float* dsrc; int dstride, dh;
  if (slot < 48) { dh = slot >> 2;     dsrc = raw + 384 + slot*4;  dstride = 1152; }
  else           { dh = (slot-48) / 6; dsrc = vpts + (slot-48)*4;  dstride = 288;  }
  float da0 = 0.f, da1 = 0.f, da2 = 0.f, da3 = 0.f;

  const float* zrow = z + (size_t)n*768*128;
  int ssm = t >> 5, ssc = t & 31;  // staging: rows i*8+ssm, col-quad ssc

  float4 zst[8];
  #define STAGE_LOAD(M0)                                                     \
    _Pragma("unroll")                                                        \
    for (int i = 0; i < 8; ++i)                                              \
      zst[i] = *(const float4*)(zrow + (size_t)((M0) + i*8 + ssm)*128 + ssc*4);
  #define STAGE_WRITE()                                                      \
    _Pragma("unroll")                                                        \
    for (int i = 0; i < 8; ++i) {                                            \
      unsigned w0 = f2bf2(zst[i].x, zst[i].y);                               \
      unsigned w1 = f2bf2(zst[i].z, zst[i].w);                               \
      uint2 uu; uu.x = w0; uu.y = w1;                                        \
      *(uint2*)&smem[Z_L + (i*8 + ssm)*68 + ssc*2] = uu;                     \
    }

  const size_t slb = (size_t)n * 9216 + (size_t)hb * 4608;  // slog base (12 f32/row)
  float4 sl, slnext;

  STAGE_LOAD(hb*384);
  if (t < 192) sl = *(const float4*)(slog + slb + t*4);
  STAGE_WRITE();
  BAR_LDS();

  for (int it = 0; it < 6; ++it) {
    int m0 = hb*384 + it*64;
    if (it < 5) {
      STAGE_LOAD(m0 + 64);                                   // stays in flight
      if (t < 192) slnext = *(const float4*)(slog + slb + (size_t)(it+1)*768 + t*4);
    }

    // ---- B1: bias[m][h] = bf16 MFMA z_tile @ Wb ----
    {
      f32x4 bacc = (f32x4){0.f,0.f,0.f,0.f};
      int zbase = (wid*16 + l15)*68;
      #pragma unroll
      for (int ks = 0; ks < 4; ++ks) {
        short8 za = *(const short8*)&smem[Z_L + zbase + kg*4 + ks*16];
        bacc = __builtin_amdgcn_mfma_f32_16x16x32_bf16(za, wbf[ks], bacc, 0, 0, 0);
      }
      #pragma unroll
      for (int r = 0; r < 4; ++r)
        smf[BIASL + (wid*16 + kg*4 + r)*17 + l15] = bacc[r];
    }
    BAR_LDS();

    // ---- B2: p = exp(sl + bias); write pt bf16 [h][m] ----
    if (t < 192) {
      float slv[4] = {sl.x, sl.y, sl.z, sl.w};
      #pragma unroll
      for (int e = 0; e < 4; ++e) {
        int ge = t*4 + e;
        int m = ge / 12, h = ge - m*12;
        float p = __expf(slv[e] + smf[BIASL + m*17 + h]);
        lds16[PT*2 + h*72 + m] = f2bf1(p);
      }
    }
    BAR_LDS();

    // ---- SM: softmax denominator (wave 0), from pt bf16 ----
    if (t < 48) {
      int h = t >> 2, seg = t & 3;
      short8 a0 = *(const short8*)&lds16[PT*2 + h*72 + seg*16];
      short8 a1 = *(const short8*)&lds16[PT*2 + h*72 + seg*16 + 8];
      float ps = 0.f;
      #pragma unroll
      for (int e = 0; e < 8; ++e)
        ps += bf2f((unsigned short)a0[e]) + bf2f((unsigned short)a1[e]);
      ps += __shfl_xor(ps, 1);
      ps += __shfl_xor(ps, 2);
      if (seg == 0) smf[S_L + h] += ps;
    }

    // ---- C: o_pair via MFMA: A = p_t[h][m], B = z_l[m][zc] (scattered u16) ----
    {
      short8 af[2];
      #pragma unroll
      for (int ks = 0; ks < 2; ++ks)
        af[ks] = *(const short8*)&lds16[PT*2 + l15*72 + ks*32 + kg*8];
      #pragma unroll
      for (int tt = 0; tt < 2; ++tt) {
        int zc = (wid*2 + tt)*16 + l15;
        #pragma unroll
        for (int ks = 0; ks < 2; ++ks) {
          short8 bf;
          #pragma unroll
          for (int e = 0; e < 8; ++e)
            bf[e] = (short)lds16[Z_L*2 + (ks*32 + kg*8 + e)*136 + zc];
          oacc[tt] = __builtin_amdgcn_mfma_f32_16x16x32_bf16(af[ks], bf, oacc[tt], 0, 0, 0);
        }
      }
    }

    // ---- D: o / o_pts accumulate (p from pt bf16) ----
    if (dact) {
      #pragma unroll
      for (int j4 = 0; j4 < 4; ++j4) {
        short8 pw = *(const short8*)&lds16[PT*2 + dh*72 + mh*32 + j4*8];
        #pragma unroll
        for (int e = 0; e < 8; ++e) {
          float wq = bf2f((unsigned short)pw[e]);
          int row = m0 + mh*32 + j4*8 + e;
          float4 v = *(const float4*)(dsrc + (size_t)row*dstride);
          da0 += wq*v.x; da1 += wq*v.y; da2 += wq*v.z; da3 += wq*v.w;
        }
      }
    }

    if (it < 5) {
      BAR_LDS();
      STAGE_WRITE();
      if (t < 192) sl = slnext;
    }
    BAR_LDS();
  }

  // ---- finalize: dump partials ----
  float* pb = part2 + (size_t)bx * 2508;
  if (t < 12) pb[t] = smf[S_L + t];
  if (dact) {
    float4 dv; dv.x = da0; dv.y = da1; dv.z = da2; dv.w = da3;
    *(float4*)(pb + 12 + (mh*120 + slot)*4) = dv;
  }
  if (kg < 3) {
    #pragma unroll
    for (int tt = 0; tt < 2; ++tt) {
      int zc = (wid*2 + tt)*16 + l15;
      #pragma unroll
      for (int r = 0; r < 4; ++r)
        pb[972 + (kg*4 + r)*128 + zc] = oacc[tt][r];
    }
  }
}

// ---------------- kernel 5: combine halves, normalize, inverse-frame -> catb (bf16) ----------------
__global__ __launch_bounds__(256) void combine(
    const float* __restrict__ part2, const float* __restrict__ Rg,
    const float* __restrict__ tg, unsigned short* __restrict__ catb)
{
  int n = blockIdx.x, t = threadIdx.x;
  const float* b0 = part2 + (size_t)n*2*2508;
  const float* b1 = b0 + 2508;
  __shared__ float S[12], ogl[288];
  if (t < 12) S[t] = b0[t] + b1[t];
  __syncthreads();
  unsigned short* cb = catb + (size_t)n*2016;
  for (int i = t; i < 480; i += 256) {
    float v = b0[12+i] + b0[12+480+i] + b1[12+i] + b1[12+480+i];
    int slot = i >> 2;
    int dh = (slot < 48) ? (slot >> 2) : ((slot - 48) / 6);
    float val = v / S[dh];
    if (i < 192) cb[i] = f2bf1(val);
    else         ogl[i - 192] = val;
  }
  __syncthreads();
  const float* R9 = Rg + n*9;
  const float* tv = tg + n*3;
  for (int j = t; j < 288; j += 256) {
    int x = j % 3, base = j - x;
    float g0 = ogl[base+0] - tv[0];
    float g1 = ogl[base+1] - tv[1];
    float g2 = ogl[base+2] - tv[2];
    cb[192 + j] = f2bf1(R9[x]*g0 + R9[3+x]*g1 + R9[6+x]*g2);   // R^T (g - t)
  }
  for (int e = t; e < 1536; e += 256) {
    int h = e >> 7;
    cb[480 + e] = f2bf1((b0[972+e] + b1[972+e]) / S[h]);
  }
}

// ---------------- kernel 6: out = catb @ WT^T + b_out via bf16 MFMA ----------------
__global__ __launch_bounds__(256) void final_mfma(
    const unsigned short* __restrict__ catb, const unsigned short* __restrict__ WT,
    const float* __restrict__ bout, float* __restrict__ out)
{
  int t = threadIdx.x, b = blockIdx.x;
  int rt = b / 6, ct = b % 6;
  int r0 = rt*64, c0 = ct*64;
  int lane = t & 63, wid = t >> 6;
  int l15 = lane & 15, kg = lane >> 4;

  f32x4 acc[4];
  #pragma unroll
  for (int cs = 0; cs < 4; ++cs) acc[cs] = (f32x4){0.f,0.f,0.f,0.f};

  const unsigned short* arow = catb + (size_t)(r0 + wid*16 + l15)*2016;
  for (int k0 = 0; k0 < 2016; k0 += 32) {
    short8 af = *(const short8*)(arow + k0 + kg*8);
    #pragma unroll
    for (int cs = 0; cs < 4; ++cs) {
      short8 bf = *(const short8*)(WT + (size_t)(c0 + cs*16 + l15)*2016 + k0 + kg*8);
      acc[cs] = __builtin_amdgcn_mfma_f32_16x16x32_bf16(af, bf, acc[cs], 0, 0, 0);
    }
  }
  #pragma unroll
  for (int cs = 0; cs < 4; ++cs) {
    #pragma unroll
    for (int r = 0; r < 4; ++r) {
      int nn = r0 + wid*16 + kg*4 + r;
      int c  = c0 + cs*16 + l15;
      out[(size_t)nn*384 + c] = acc[cs][r] + bout[c];
    }
  }
}

extern "C" void kernel_launch(void* const* d_in, const int* in_sizes, int n_in,
                              void* d_out, int out_size, void* d_ws, size_t ws_size,
                              hipStream_t stream) {
  const float* s    = (const float*)d_in[0];
  const float* z    = (const float*)d_in[1];
  const float* R    = (const float*)d_in[2];
  const float* tv   = (const float*)d_in[3];
  const float* Wq   = (const float*)d_in[4];
  const float* Wk   = (const float*)d_in[5];
  const float* Wv   = (const float*)d_in[6];
  const float* Wqp  = (const float*)d_in[7];
  const float* Wkp  = (const float*)d_in[8];
  const float* Wvp  = (const float*)d_in[9];
  const float* Wb   = (const float*)d_in[10];
  const float* Wout = (const float*)d_in[11];
  const float* bout = (const float*)d_in[12];
  float* out = (float*)d_out;
  float* ws  = (float*)d_ws;

  float* raw  = ws + RAW_OFF;
  float* vpts = ws + VPTS_OFF;
  float* kn   = ws + KN_OFF;
  unsigned short* catb = (unsigned short*)(ws + CAT_OFF);
  short* Qp   = (short*)(ws + QP_OFF);
  short* Kp   = (short*)(ws + KP_OFF);
  float* slog = ws + SLOG_OFF;
  float* part2 = ws + PART2_OFF;
  unsigned short* WT = (unsigned short*)(ws + WT_OFF);
  unsigned short* sb = (unsigned short*)(ws + SB_OFF);
  unsigned short* wtc = (unsigned short*)(ws + WTC_OFF);

  // input-only converts first (overlap whatever follows)
  scvt<<<288, 256, 0, stream>>>(s, sb);
  wcatcvt<<<432, 256, 0, stream>>>(Wq, Wk, Wv, Wqp, Wkp, Wvp, wtc);
  wcvt<<<756, 256, 0, stream>>>(Wout, WT);

  prep_mfma<<<216, 256, 0, stream>>>(sb, wtc, raw);
  transform_qk<<<768, 256, 0, stream>>>(raw, R, tv, vpts, kn, Qp, Kp);
  logits_gemm<<<144, 512, 0, stream>>>(Qp, Kp, kn, slog);
  ipa_main<<<1536, 256, 0, stream>>>(z, raw, slog, vpts, Wb, part2);
  combine<<<768, 256, 0, stream>>>(part2, R, tv, catb);
  final_mfma<<<72, 256, 0, stream>>>(catb, WT, bout, out);
}

// Round 16
// 179.160 us; speedup vs baseline: 1.3031x; 1.1252x over previous
//
#include <hip/hip_runtime.h>
#include <math.h>

// IPA: B=1, N=768, H=12, C=16, PQ=4, PV=8, C_S=384, C_Z=128
// ws layout (floats); bf16 buffers consume elemcount/2 f32 slots (R14 lesson).
#define RAW_OFF    0u          // f32 [768][1152] q|k|v|qp|kp|vp          (884736)
#define VALL_OFF   884736u     // bf16 [768][512] v|vpts = 393216 u16     (196608)
#define KN_OFF     1081344u    // f32 [768][12]                           (9216)
#define CAT_OFF    1090560u    // bf16 [768][2016] = 1548288 u16          (774144)
#define QP_OFF     1864704u    // bf16 [768][12][32] = 294912 u16         (147456)
#define KP_OFF     2012160u    // bf16                                    (147456)
#define SLOG_OFF   2159616u    // f32 [768][768][12]                      (7077888)
#define PART2_OFF  9237504u    // f32 [1536][2508]                        (3852288)
#define WT_OFF     13089792u   // bf16 [384][2016] = 774144 u16           (387072)
#define SB_OFF     13476864u   // bf16 [768][384] = 294912 u16            (147456)
#define WTC_OFF    13624320u   // bf16 [1152][384] = 442368 u16           (221184)
// total 13,845,504 floats = 55.4 MB

#define WL 0.5773502691896258f
#define WC 0.23570226039551587f
#define CKN (-0.5f*WL*WC)

typedef __attribute__((ext_vector_type(8))) short short8;
typedef __attribute__((ext_vector_type(4))) float f32x4;

__device__ __forceinline__ unsigned short f2bf1(float a) {
  unsigned u = __builtin_bit_cast(unsigned, a);
  return (unsigned short)((u + 0x7fff + ((u >> 16) & 1)) >> 16);
}
__device__ __forceinline__ unsigned f2bf2(float a, float b) {
  unsigned ua = __builtin_bit_cast(unsigned, a), ub = __builtin_bit_cast(unsigned, b);
  return (unsigned)((ua + 0x7fff + ((ua >> 16) & 1)) >> 16)
       | ((ub + 0x7fff + ((ub >> 16) & 1)) & 0xffff0000u);
}
__device__ __forceinline__ float bf2f(unsigned short u) {
  return __builtin_bit_cast(float, ((unsigned)u) << 16);
}
__device__ __forceinline__ float bflo(unsigned u) { return __builtin_bit_cast(float, u << 16); }
__device__ __forceinline__ float bfhi(unsigned u) { return __builtin_bit_cast(float, u & 0xffff0000u); }

// LDS-only barrier in ONE asm (raw s_barrier is not a compiler fence).
// Leaves global loads (vmcnt) in flight across it.
#define BAR_LDS() asm volatile("s_waitcnt lgkmcnt(0)\n\ts_barrier" ::: "memory")

// ---------------- kernel 0: all input converts, grid-sectioned ----------------
// sections: [0,288) scvt, [288,720) wcatcvt, [720,1476) wcvt
__global__ __launch_bounds__(256) void cvt_all(
    const float* __restrict__ s,
    const float* __restrict__ Wq, const float* __restrict__ Wk, const float* __restrict__ Wv,
    const float* __restrict__ Wqp, const float* __restrict__ Wkp, const float* __restrict__ Wvp,
    const float* __restrict__ Wout,
    unsigned short* __restrict__ sb, unsigned short* __restrict__ wtc,
    unsigned short* __restrict__ WT)
{
  __shared__ float tl[32][33];
  int b = blockIdx.x, t = threadIdx.x;
  if (b < 288) {                     // s -> bf16
    int g = b*256 + t;
    float4 v = *(const float4*)(s + (size_t)g*4);
    uint2 p; p.x = f2bf2(v.x, v.y); p.y = f2bf2(v.z, v.w);
    *(uint2*)(sb + (size_t)g*4) = p;
  } else if (b < 720) {              // [Wq|..|Wvp]^T -> bf16 wtc[1152][384]
    int g = (b-288)*256 + t;
    int c = g / 96, kq = (g % 96) * 4;
    const float* W; int od, cl;
    if (c < 192)      { W = Wq;  od = 192; cl = c; }
    else if (c < 384) { W = Wk;  od = 192; cl = c - 192; }
    else if (c < 576) { W = Wv;  od = 192; cl = c - 384; }
    else if (c < 720) { W = Wqp; od = 144; cl = c - 576; }
    else if (c < 864) { W = Wkp; od = 144; cl = c - 720; }
    else              { W = Wvp; od = 288; cl = c - 864; }
    float a = W[(size_t)(kq+0)*od + cl];
    float bb = W[(size_t)(kq+1)*od + cl];
    float d = W[(size_t)(kq+2)*od + cl];
    float e = W[(size_t)(kq+3)*od + cl];
    uint2 p; p.x = f2bf2(a, bb); p.y = f2bf2(d, e);
    *(uint2*)(wtc + (size_t)c*384 + kq) = p;
  } else {                           // W_out^T -> bf16 WT[384][2016]
    int bb = b - 720;
    int kt = bb % 63, ct = bb / 63;
    int k0 = kt*32, c0 = ct*32;
    int tr = t >> 5, tc = t & 31;
    #pragma unroll
    for (int i = 0; i < 4; ++i)
      tl[tr + i*8][tc] = Wout[(size_t)(k0 + tr + i*8)*384 + c0 + tc];
    __syncthreads();
    #pragma unroll
    for (int i = 0; i < 4; ++i) {
      int c = tr + i*8;
      WT[(size_t)(c0 + c)*2016 + k0 + tc] = f2bf1(tl[tc][c]);
    }
  }
}

// ---------------- kernel 1: raw = s @ Wcat via bf16 MFMA (no LDS; L2-resident) ----------------
__global__ __launch_bounds__(256) void prep_mfma(
    const unsigned short* __restrict__ sb, const unsigned short* __restrict__ wtc,
    float* __restrict__ raw)
{
  int t = threadIdx.x, b = blockIdx.x;
  int ct = b % 18, rt = b / 18;
  int lane = t & 63, wid = t >> 6;
  int l15 = lane & 15, kg = lane >> 4;
  int r0 = rt*64 + wid*16, c0 = ct*64;

  f32x4 acc[4];
  #pragma unroll
  for (int cs = 0; cs < 4; ++cs) acc[cs] = (f32x4){0.f,0.f,0.f,0.f};

  for (int k0 = 0; k0 < 384; k0 += 32) {
    short8 af = *(const short8*)(sb + (size_t)(r0 + l15)*384 + k0 + kg*8);
    #pragma unroll
    for (int cs = 0; cs < 4; ++cs) {
      short8 bf = *(const short8*)(wtc + (size_t)(c0 + cs*16 + l15)*384 + k0 + kg*8);
      acc[cs] = __builtin_amdgcn_mfma_f32_16x16x32_bf16(af, bf, acc[cs], 0, 0, 0);
    }
  }
  #pragma unroll
  for (int cs = 0; cs < 4; ++cs)
    #pragma unroll
    for (int r = 0; r < 4; ++r)
      raw[(size_t)(r0 + kg*4 + r)*1152 + c0 + cs*16 + l15] = acc[cs][r];
}

// ---------------- kernel 2: frame transform + kn + Qp/Kp + vall bf16 ----------------
__global__ __launch_bounds__(256) void transform_qk(
    const float* __restrict__ raw, const float* __restrict__ R, const float* __restrict__ tg,
    float* __restrict__ kn, short* __restrict__ Qp, short* __restrict__ Kp,
    unsigned short* __restrict__ vall)
{
  int n = blockIdx.x, t = threadIdx.x;
  __shared__ float tl[576];
  const float* R9 = R + n*9;
  const float* tv = tg + n*3;
  #pragma unroll
  for (int i = 0; i < 3; ++i) {
    int j = i*256 + t;
    if (j >= 576) break;
    int jj, basecol;
    if (j < 144)      { jj = j;      basecol = 576; }
    else if (j < 288) { jj = j-144;  basecol = 720; }
    else              { jj = j-288;  basecol = 864; }
    int x = jj % 3;
    const float* p = raw + n*1152 + basecol + (jj - x);
    float val = R9[x*3+0]*p[0] + R9[x*3+1]*p[1] + R9[x*3+2]*p[2] + tv[x];
    tl[j] = val;
  }
  __syncthreads();
  if (t < 12) {
    const float* q = tl + 144 + t*12;
    float sm = 0.f;
    #pragma unroll
    for (int r = 0; r < 12; ++r) sm += q[r]*q[r];
    kn[n*12 + t] = sm;
  }
  // vall[n][c]: c<192 = v (raw cols 384..575), c in 192..479 = vpts (global frame)
  for (int c = t; c < 480; c += 256) {
    float val = (c < 192) ? raw[n*1152 + 384 + c] : tl[288 + (c - 192)];
    vall[(size_t)n*512 + c] = f2bf1(val);
  }
  #pragma unroll
  for (int i = 0; i < 2; ++i) {
    int idx = i*256 + t;
    if (idx >= 384) break;
    int h = idx >> 5, k = idx & 31;
    float qv, kv;
    if (k < 16)      { qv = (WL*0.25f) * raw[n*1152 + h*16 + k];  kv = raw[n*1152 + 192 + h*16 + k]; }
    else if (k < 28) { qv = (WL*WC) * tl[h*12 + (k-16)];          kv = tl[144 + h*12 + (k-16)]; }
    else             { qv = 0.f; kv = 0.f; }
    Qp[n*384 + idx] = (short)f2bf1(qv);
    Kp[n*384 + idx] = (short)f2bf1(kv);
  }
}

// ---------------- kernel 3: slog = logits via per-h bf16 MFMA GEMM ----------------
__global__ __launch_bounds__(512) void logits_gemm(
    const short* __restrict__ Qp, const short* __restrict__ Kp,
    const float* __restrict__ kn, float* __restrict__ slog)
{
  int t = threadIdx.x, b = blockIdx.x;
  int bn = b / 12, bm = b % 12;
  int lane = t & 63, wid = t >> 6;
  int nsub = wid & 3, msub = wid >> 2;
  int l15 = lane & 15, kg = lane >> 4;
  int nrow = bn*64 + nsub*16 + l15;
  int mbase = bm*64 + msub*32;

  f32x4 acc[2][12];
  #pragma unroll
  for (int mt = 0; mt < 2; ++mt)
    #pragma unroll
    for (int h = 0; h < 12; ++h) acc[mt][h] = (f32x4){0.f,0.f,0.f,0.f};

  #pragma unroll
  for (int h = 0; h < 12; ++h) {
    short8 af = *(const short8*)(Qp + (size_t)(nrow*12 + h)*32 + kg*8);
    #pragma unroll
    for (int mt = 0; mt < 2; ++mt) {
      int m = mbase + mt*16 + l15;
      short8 bf = *(const short8*)(Kp + (size_t)(m*12 + h)*32 + kg*8);
      acc[mt][h] = __builtin_amdgcn_mfma_f32_16x16x32_bf16(af, bf, acc[mt][h], 0, 0, 0);
    }
  }
  #pragma unroll
  for (int mt = 0; mt < 2; ++mt) {
    int m = mbase + mt*16 + l15;
    float knadj[12];
    #pragma unroll
    for (int h = 0; h < 12; ++h) knadj[h] = CKN * kn[m*12 + h];
    #pragma unroll
    for (int r = 0; r < 4; ++r) {
      int nr = bn*64 + nsub*16 + kg*4 + r;
      size_t base = ((size_t)nr*768 + m)*12;
      #pragma unroll
      for (int hq = 0; hq < 3; ++hq) {
        float4 v;
        v.x = acc[mt][hq*4+0][r] + knadj[hq*4+0];
        v.y = acc[mt][hq*4+1][r] + knadj[hq*4+1];
        v.z = acc[mt][hq*4+2][r] + knadj[hq*4+2];
        v.w = acc[mt][hq*4+3][r] + knadj[hq*4+3];
        *(float4*)(slog + base + hq*4) = v;
      }
    }
  }
}

// ---------------- kernel 4: fused attention core (R15 structure; D reads vall bf16) ----
// grid 1536: block bx -> (n = bx>>1, hb = bx&1); each handles 6 of 12 m-tiles.
// LDS words: z_l bf16 [64][68w], bias[64][17], pt bf16 [16][72], S[12]
#define Z_L   0
#define BIASL 4352
#define PT    5440
#define S_L   6016
#define SMEMW 6028

// launch_bounds min-waves MUST stay <= 2: at >=3 the compiler targets a 64-85
// VGPR budget and spills the 32-reg zst prefetch to scratch (R5 AND R9 both
// hit this: WRITE_SIZE ~0.5 GB, 2x slowdown). VGPR ~112 needs the 2-wave cap.
__global__ __launch_bounds__(256, 2) void ipa_main(
    const float* __restrict__ z, const float* __restrict__ slog,
    const unsigned short* __restrict__ vall, const float* __restrict__ Wb,
    float* __restrict__ part2)
{
  __shared__ __align__(16) unsigned smem[SMEMW];
  float* smf = (float*)smem;
  unsigned short* lds16 = (unsigned short*)smem;
  int bx = blockIdx.x;
  int n = bx >> 1, hb = bx & 1;
  int t = threadIdx.x;
  int lane = t & 63, wid = t >> 6;
  int l15 = lane & 15, kg = lane >> 4;

  if (t < 12) smf[S_L + t] = 0.f;

  // Wb B-fragments (WL folded), bf16
  short8 wbf[4];
  {
    #pragma unroll
    for (int ks = 0; ks < 4; ++ks)
      #pragma unroll
      for (int e = 0; e < 8; ++e) {
        int kk = ks*32 + kg*8 + e;
        float v = (l15 < 12) ? WL * Wb[kk*12 + l15] : 0.f;
        wbf[ks][e] = (short)f2bf1(v);
      }
  }

  // C-phase (MFMA): wave owns zc-tiles {wid*2, wid*2+1}
  f32x4 oacc[2];
  oacc[0] = (f32x4){0.f,0.f,0.f,0.f};
  oacc[1] = (f32x4){0.f,0.f,0.f,0.f};

  // D-phase: 120 col-quads of vall (bf16) x 2 m-halves
  bool dact = t < 240;
  int mh = t / 120, slot = t % 120;
  int dcol = (slot < 48) ? slot*4 : 192 + (slot-48)*4;
  int dh   = (slot < 48) ? (slot >> 2) : (slot-48)/6;
  const unsigned short* dsrc = vall + dcol;
  float da0 = 0.f, da1 = 0.f, da2 = 0.f, da3 = 0.f;

  const float* zrow = z + (size_t)n*768*128;
  int ssm = t >> 5, ssc = t & 31;  // staging: rows i*8+ssm, col-quad ssc

  float4 zst[8];
  #define STAGE_LOAD(M0)                                                     \
    _Pragma("unroll")                                                        \
    for (int i = 0; i < 8; ++i)                                              \
      zst[i] = *(const float4*)(zrow + (size_t)((M0) + i*8 + ssm)*128 + ssc*4);
  #define STAGE_WRITE()                                                      \
    _Pragma("unroll")                                                        \
    for (int i = 0; i < 8; ++i) {                                            \
      unsigned w0 = f2bf2(zst[i].x, zst[i].y);                               \
      unsigned w1 = f2bf2(zst[i].z, zst[i].w);                               \
      uint2 uu; uu.x = w0; uu.y = w1;                                        \
      *(uint2*)&smem[Z_L + (i*8 + ssm)*68 + ssc*2] = uu;                     \
    }

  const size_t slb = (size_t)n * 9216 + (size_t)hb * 4608;  // slog base (12 f32/row)
  float4 sl, slnext;

  STAGE_LOAD(hb*384);
  if (t < 192) sl = *(const float4*)(slog + slb + t*4);
  STAGE_WRITE();
  BAR_LDS();

  for (int it = 0; it < 6; ++it) {
    int m0 = hb*384 + it*64;
    if (it < 5) {
      STAGE_LOAD(m0 + 64);                                   // stays in flight
      if (t < 192) slnext = *(const float4*)(slog + slb + (size_t)(it+1)*768 + t*4);
    }

    // ---- B1: bias[m][h] = bf16 MFMA z_tile @ Wb ----
    {
      f32x4 bacc = (f32x4){0.f,0.f,0.f,0.f};
      int zbase = (wid*16 + l15)*68;
      #pragma unroll
      for (int ks = 0; ks < 4; ++ks) {
        short8 za = *(const short8*)&smem[Z_L + zbase + kg*4 + ks*16];
        bacc = __builtin_amdgcn_mfma_f32_16x16x32_bf16(za, wbf[ks], bacc, 0, 0, 0);
      }
      #pragma unroll
      for (int r = 0; r < 4; ++r)
        smf[BIASL + (wid*16 + kg*4 + r)*17 + l15] = bacc[r];
    }
    BAR_LDS();

    // ---- B2: p = exp(sl + bias); write pt bf16 [h][m] ----
    if (t < 192) {
      float slv[4] = {sl.x, sl.y, sl.z, sl.w};
      #pragma unroll
      for (int e = 0; e < 4; ++e) {
        int ge = t*4 + e;
        int m = ge / 12, h = ge - m*12;
        float p = __expf(slv[e] + smf[BIASL + m*17 + h]);
        lds16[PT*2 + h*72 + m] = f2bf1(p);
      }
    }
    BAR_LDS();

    // ---- SM: softmax denominator (wave 0), from pt bf16 ----
    if (t < 48) {
      int h = t >> 2, seg = t & 3;
      short8 a0 = *(const short8*)&lds16[PT*2 + h*72 + seg*16];
      short8 a1 = *(const short8*)&lds16[PT*2 + h*72 + seg*16 + 8];
      float ps = 0.f;
      #pragma unroll
      for (int e = 0; e < 8; ++e)
        ps += bf2f((unsigned short)a0[e]) + bf2f((unsigned short)a1[e]);
      ps += __shfl_xor(ps, 1);
      ps += __shfl_xor(ps, 2);
      if (seg == 0) smf[S_L + h] += ps;
    }

    // ---- C: o_pair via MFMA: A = p_t[h][m], B = z_l[m][zc] (scattered u16) ----
    {
      short8 af[2];
      #pragma unroll
      for (int ks = 0; ks < 2; ++ks)
        af[ks] = *(const short8*)&lds16[PT*2 + l15*72 + ks*32 + kg*8];
      #pragma unroll
      for (int tt = 0; tt < 2; ++tt) {
        int zc = (wid*2 + tt)*16 + l15;
        #pragma unroll
        for (int ks = 0; ks < 2; ++ks) {
          short8 bf;
          #pragma unroll
          for (int e = 0; e < 8; ++e)
            bf[e] = (short)lds16[Z_L*2 + (ks*32 + kg*8 + e)*136 + zc];
          oacc[tt] = __builtin_amdgcn_mfma_f32_16x16x32_bf16(af[ks], bf, oacc[tt], 0, 0, 0);
        }
      }
    }

    // ---- D: o / o_pts accumulate (vall bf16, uint2 per row) ----
    if (dact) {
      #pragma unroll
      for (int j4 = 0; j4 < 4; ++j4) {
        short8 pw = *(const short8*)&lds16[PT*2 + dh*72 + mh*32 + j4*8];
        #pragma unroll
        for (int e = 0; e < 8; ++e) {
          float wq = bf2f((unsigned short)pw[e]);
          int row = m0 + mh*32 + j4*8 + e;
          uint2 vv = *(const uint2*)(dsrc + (size_t)row*512);
          da0 += wq*bflo(vv.x); da1 += wq*bfhi(vv.x);
          da2 += wq*bflo(vv.y); da3 += wq*bfhi(vv.y);
        }
      }
    }

    if (it < 5) {
      BAR_LDS();
      STAGE_WRITE();
      if (t < 192) sl = slnext;
    }
    BAR_LDS();
  }

  // ---- finalize: dump partials ----
  float* pb = part2 + (size_t)bx * 2508;
  if (t < 12) pb[t] = smf[S_L + t];
  if (dact) {
    float4 dv; dv.x = da0; dv.y = da1; dv.z = da2; dv.w = da3;
    *(float4*)(pb + 12 + (mh*120 + slot)*4) = dv;
  }
  if (kg < 3) {
    #pragma unroll
    for (int tt = 0; tt < 2; ++tt) {
      int zc = (wid*2 + tt)*16 + l15;
      #pragma unroll
      for (int r = 0; r < 4; ++r)
        pb[972 + (kg*4 + r)*128 + zc] = oacc[tt][r];
    }
  }
}

// ---------------- kernel 5: combine halves, normalize, inverse-frame -> catb (bf16) ----------------
__global__ __launch_bounds__(256) void combine(
    const float* __restrict__ part2, const float* __restrict__ Rg,
    const float* __restrict__ tg, unsigned short* __restrict__ catb)
{
  int n = blockIdx.x, t = threadIdx.x;
  const float* b0 = part2 + (size_t)n*2*2508;
  const float* b1 = b0 + 2508;
  __shared__ float S[12], ogl[288];
  if (t < 12) S[t] = b0[t] + b1[t];
  __syncthreads();
  unsigned short* cb = catb + (size_t)n*2016;
  for (int i = t; i < 480; i += 256) {
    float v = b0[12+i] + b0[12+480+i] + b1[12+i] + b1[12+480+i];
    int slot = i >> 2;
    int dh = (slot < 48) ? (slot >> 2) : ((slot - 48) / 6);
    float val = v / S[dh];
    if (i < 192) cb[i] = f2bf1(val);
    else         ogl[i - 192] = val;
  }
  __syncthreads();
  const float* R9 = Rg + n*9;
  const float* tv = tg + n*3;
  for (int j = t; j < 288; j += 256) {
    int x = j % 3, base = j - x;
    float g0 = ogl[base+0] - tv[0];
    float g1 = ogl[base+1] - tv[1];
    float g2 = ogl[base+2] - tv[2];
    cb[192 + j] = f2bf1(R9[x]*g0 + R9[3+x]*g1 + R9[6+x]*g2);   // R^T (g - t)
  }
  for (int e = t; e < 1536; e += 256) {
    int h = e >> 7;
    cb[480 + e] = f2bf1((b0[972+e] + b1[972+e]) / S[h]);
  }
}

// ---------------- kernel 6: out = catb @ WT^T + b_out via bf16 MFMA ----------------
__global__ __launch_bounds__(256) void final_mfma(
    const unsigned short* __restrict__ catb, const unsigned short* __restrict__ WT,
    const float* __restrict__ bout, float* __restrict__ out)
{
  int t = threadIdx.x, b = blockIdx.x;
  int rt = b / 6, ct = b % 6;
  int r0 = rt*64, c0 = ct*64;
  int lane = t & 63, wid = t >> 6;
  int l15 = lane & 15, kg = lane >> 4;

  f32x4 acc[4];
  #pragma unroll
  for (int cs = 0; cs < 4; ++cs) acc[cs] = (f32x4){0.f,0.f,0.f,0.f};

  const unsigned short* arow = catb + (size_t)(r0 + wid*16 + l15)*2016;
  for (int k0 = 0; k0 < 2016; k0 += 32) {
    short8 af = *(const short8*)(arow + k0 + kg*8);
    #pragma unroll
    for (int cs = 0; cs < 4; ++cs) {
      short8 bf = *(const short8*)(WT + (size_t)(c0 + cs*16 + l15)*2016 + k0 + kg*8);
      acc[cs] = __builtin_amdgcn_mfma_f32_16x16x32_bf16(af, bf, acc[cs], 0, 0, 0);
    }
  }
  #pragma unroll
  for (int cs = 0; cs < 4; ++cs) {
    #pragma unroll
    for (int r = 0; r < 4; ++r) {
      int nn = r0 + wid*16 + kg*4 + r;
      int c  = c0 + cs*16 + l15;
      out[(size_t)nn*384 + c] = acc[cs][r] + bout[c];
    }
  }
}

extern "C" void kernel_launch(void* const* d_in, const int* in_sizes, int n_in,
                              void* d_out, int out_size, void* d_ws, size_t ws_size,
                              hipStream_t stream) {
  const float* s    = (const float*)d_in[0];
  const float* z    = (const float*)d_in[1];
  const float* R    = (const float*)d_in[2];
  const float* tv   = (const float*)d_in[3];
  const float* Wq   = (const float*)d_in[4];
  const float* Wk   = (const float*)d_in[5];
  const float* Wv   = (const float*)d_in[6];
  const float* Wqp  = (const float*)d_in[7];
  const float* Wkp  = (const float*)d_in[8];
  const float* Wvp  = (const float*)d_in[9];
  const float* Wb   = (const float*)d_in[10];
  const float* Wout = (const float*)d_in[11];
  const float* bout = (const float*)d_in[12];
  float* out = (float*)d_out;
  float* ws  = (float*)d_ws;

  float* raw  = ws + RAW_OFF;
  unsigned short* vall = (unsigned short*)(ws + VALL_OFF);
  float* kn   = ws + KN_OFF;
  unsigned short* catb = (unsigned short*)(ws + CAT_OFF);
  short* Qp   = (short*)(ws + QP_OFF);
  short* Kp   = (short*)(ws + KP_OFF);
  float* slog = ws + SLOG_OFF;
  float* part2 = ws + PART2_OFF;
  unsigned short* WT = (unsigned short*)(ws + WT_OFF);
  unsigned short* sb = (unsigned short*)(ws + SB_OFF);
  unsigned short* wtc = (unsigned short*)(ws + WTC_OFF);

  cvt_all<<<1476, 256, 0, stream>>>(s, Wq, Wk, Wv, Wqp, Wkp, Wvp, Wout, sb, wtc, WT);
  prep_mfma<<<216, 256, 0, stream>>>(sb, wtc, raw);
  transform_qk<<<768, 256, 0, stream>>>(raw, R, tv, kn, Qp, Kp, vall);
  logits_gemm<<<144, 512, 0, stream>>>(Qp, Kp, kn, slog);
  ipa_main<<<1536, 256, 0, stream>>>(z, slog, vall, Wb, part2);
  combine<<<768, 256, 0, stream>>>(part2, R, tv, catb);
  final_mfma<<<72, 256, 0, stream>>>(catb, WT, bout, out);
}